// Round 5
// baseline (4803.601 us; speedup 1.0000x reference)
//
#include <hip/hip_runtime.h>

constexpr int NN = 500000;
constexpr int NE = 16000000;
constexpr int BN = 256;                    // dst nodes per bucket
constexpr int NBUCK = (NN + BN - 1) / BN;  // 1954
constexpr int NSUB = 8;                    // one sub-buffer per XCD
constexpr int CAP = 1472;                  // per-(bucket,sub): mean 1023.5, 1.44x slack
constexpr int BCNT_STRIDE = 2048;          // counters laid out [sub][bucket]
constexpr int NB_NODE = (NN + 255) / 256;  // 1954

__device__ __forceinline__ int xcc_id() {
    // s_getreg hwreg(HW_REG_XCC_ID=20, offset=0, size=4) -> 20 | ((4-1)<<11) = 6164
    // [measured: learn_hip m09 on MI355X: returns 0..7]
    return __builtin_amdgcn_s_getreg(6164) & 7;
}

// ---------------- bucket edges by dst>>8 into per-XCD sub-buffers ----------------
__global__ void __launch_bounds__(256) bucket_pass(const int* __restrict__ src,
                                                   const int* __restrict__ dst,
                                                   int* __restrict__ bcnt,
                                                   int* __restrict__ bstore) {
    int e0 = (blockIdx.x * 256 + threadIdx.x) * 4;   // NE % 1024 == 0
    int sub = xcc_id();                               // true XCD of this wave
    int4 s = *(const int4*)(src + e0);
    int4 d = *(const int4*)(dst + e0);
    int sv[4] = {s.x, s.y, s.z, s.w};
    int dv[4] = {d.x, d.y, d.z, d.w};
#pragma unroll
    for (int k = 0; k < 4; ++k) {
        int b = dv[k] >> 8;
        int pos = atomicAdd(&bcnt[sub * BCNT_STRIDE + b], 1);
        if (pos < CAP)
            bstore[((size_t)sub * NBUCK + b) * CAP + pos] = (sv[k] << 8) | (dv[k] & 255);
    }
}

// ---------------- layer-1 pre-transform: x @ Wl1.T (10 -> 5) into split planes ----------------
__global__ void __launch_bounds__(256) transform0(const float* __restrict__ x,
                                                  const float* __restrict__ Wl1,
                                                  float4* __restrict__ t4,
                                                  float* __restrict__ t1) {
    int i = blockIdx.x * 256 + threadIdx.x;
    if (i >= NN) return;
    float xi[10];
#pragma unroll
    for (int k = 0; k < 10; ++k) xi[k] = x[i * 10 + k];
    float v[5];
#pragma unroll
    for (int j = 0; j < 5; ++j) {
        float a = 0.f;
#pragma unroll
        for (int k = 0; k < 10; ++k) a += xi[k] * Wl1[j * 10 + k];
        v[j] = a;
    }
    t4[i] = make_float4(v[0], v[1], v[2], v[3]);
    t1[i] = v[4];
}

// ---------------- fused edge-parallel gather (LDS accumulate) + node update ----------------
template <int FIN, int FOUT, int FNEXT, bool RELU, bool FIRST>
__global__ void __launch_bounds__(256, 8) bucket_gather(const int* __restrict__ bcnt,
                                                        const int* __restrict__ bstore,
                                                        const float4* __restrict__ t4,
                                                        const float* __restrict__ t1,
                                                        const float* __restrict__ hin,
                                                        const float* __restrict__ Wr,
                                                        const float* __restrict__ b,
                                                        const float* __restrict__ Wln,
                                                        float* __restrict__ inv,
                                                        float* __restrict__ hout,
                                                        float4* __restrict__ tn4,
                                                        float* __restrict__ tn1) {
    __shared__ float acc[BN * FOUT];
    __shared__ float scnt[FIRST ? BN : 1];
    const int bkt = blockIdx.x;
    const int tid = threadIdx.x;
    for (int k = tid; k < BN * FOUT; k += 256) acc[k] = 0.f;
    if (FIRST) scnt[tid] = 0.f;
    __syncthreads();

#pragma unroll 1
    for (int sub = 0; sub < NSUB; ++sub) {
        int n = bcnt[sub * BCNT_STRIDE + bkt];
        if (n > CAP) n = CAP;
        const int* bs = bstore + ((size_t)sub * NBUCK + bkt) * CAP;
        int k = tid;
        for (; k + 768 < n; k += 1024) {   // 4 edges in flight per thread
            int e[4] = {bs[k], bs[k + 256], bs[k + 512], bs[k + 768]};
            int dd[4];
            if constexpr (FOUT == 5) {
                float4 p[4]; float q[4];
#pragma unroll
                for (int u = 0; u < 4; ++u) {
                    int sN = e[u] >> 8; dd[u] = e[u] & 255;
                    p[u] = t4[sN]; q[u] = t1[sN];
                }
#pragma unroll
                for (int u = 0; u < 4; ++u) {
                    float* a = &acc[dd[u] * 5];
                    atomicAdd(a + 0, p[u].x); atomicAdd(a + 1, p[u].y);
                    atomicAdd(a + 2, p[u].z); atomicAdd(a + 3, p[u].w);
                    atomicAdd(a + 4, q[u]);
                    if (FIRST) atomicAdd(&scnt[dd[u]], 1.f);
                }
            } else {
                float q[4];
#pragma unroll
                for (int u = 0; u < 4; ++u) {
                    int sN = e[u] >> 8; dd[u] = e[u] & 255; q[u] = t1[sN];
                }
#pragma unroll
                for (int u = 0; u < 4; ++u) atomicAdd(&acc[dd[u]], q[u]);
            }
        }
        for (; k < n; k += 256) {          // tail
            int e0 = bs[k];
            int sN = e0 >> 8, d0 = e0 & 255;
            if constexpr (FOUT == 5) {
                float4 p = t4[sN]; float q = t1[sN];
                float* a = &acc[d0 * 5];
                atomicAdd(a + 0, p.x); atomicAdd(a + 1, p.y);
                atomicAdd(a + 2, p.z); atomicAdd(a + 3, p.w);
                atomicAdd(a + 4, q);
                if (FIRST) atomicAdd(&scnt[d0], 1.f);
            } else {
                atomicAdd(&acc[d0], t1[sN]);
            }
        }
    }
    __syncthreads();

    // ---- node update: one node per thread ----
    int node = bkt * BN + tid;
    if (node >= NN) return;
    float iv;
    if (FIRST) {
        iv = 1.0f / fmaxf(scnt[tid], 1.0f);
        inv[node] = iv;
    } else {
        iv = inv[node];
    }
    float vin[FIN];
#pragma unroll
    for (int k = 0; k < FIN; ++k) vin[k] = hin[(size_t)node * FIN + k];
    float ho[FOUT];
#pragma unroll
    for (int jo = 0; jo < FOUT; ++jo) {
        float v = acc[tid * FOUT + jo] * iv + b[jo];
#pragma unroll
        for (int k = 0; k < FIN; ++k) v += vin[k] * Wr[jo * FIN + k];
        if (RELU) v = fmaxf(v, 0.f);
        hout[(size_t)node * FOUT + jo] = v;
        ho[jo] = v;
    }
    if constexpr (FNEXT == 5) {
        float tv[5];
#pragma unroll
        for (int j2 = 0; j2 < 5; ++j2) {
            float v = 0.f;
#pragma unroll
            for (int jo = 0; jo < FOUT; ++jo) v += ho[jo] * Wln[j2 * FOUT + jo];
            tv[j2] = v;
        }
        tn4[node] = make_float4(tv[0], tv[1], tv[2], tv[3]);
        tn1[node] = tv[4];
    } else if constexpr (FNEXT == 1) {
        float v = 0.f;
#pragma unroll
        for (int jo = 0; jo < FOUT; ++jo) v += ho[jo] * Wln[jo];
        tn1[node] = v;
    }
}

extern "C" void kernel_launch(void* const* d_in, const int* in_sizes, int n_in,
                              void* d_out, int out_size, void* d_ws, size_t ws_size,
                              hipStream_t stream) {
    (void)in_sizes; (void)n_in; (void)out_size; (void)ws_size;
    const float* x    = (const float*)d_in[0];
    const int*   ei   = (const int*)d_in[1];
    const float* Wl1  = (const float*)d_in[2];
    const float* Wr1  = (const float*)d_in[3];
    const float* b1   = (const float*)d_in[4];
    const float* Wlm  = (const float*)d_in[5];
    const float* Wrm  = (const float*)d_in[6];
    const float* bm   = (const float*)d_in[7];
    const float* Wl10 = (const float*)d_in[8];
    const float* Wr10 = (const float*)d_in[9];
    const float* b10  = (const float*)d_in[10];
    float* out = (float*)d_out;

    const int* src = ei;
    const int* dst = ei + NE;

    // workspace layout (4-byte units), ~134 MB total
    int* wsI = (int*)d_ws;
    int*    bcnt   = wsI;                          // 8*2048 = 16384
    int*    bstore = wsI + 16384;                  // 8*1954*1472 = 23,010,304
    float*  inv    = (float*)(wsI + 23026688);     // 500,224
    float4* t4A    = (float4*)(wsI + 23526912);    // 4*500224
    float*  t1A    = (float*)(wsI + 25527808);     // 500,224
    float4* t4B    = (float4*)(wsI + 26028032);    // 4*500224
    float*  t1B    = (float*)(wsI + 28028928);     // 500,224
    float*  hA     = (float*)(wsI + 28529152);     // 2,500,608
    float*  hB     = (float*)(wsI + 31029760);     // 2,500,608 -> end 33,530,368

    dim3 blk(256);
    dim3 nb(NB_NODE);
    dim3 gb(NBUCK);

    // ---- bucket build ----
    hipMemsetAsync(bcnt, 0, 16384 * sizeof(int), stream);
    bucket_pass<<<dim3(NE / 1024), blk, 0, stream>>>(src, dst, bcnt, bstore);

    // ---- layer 1 (10 -> 5); counts degree, writes inv ----
    transform0<<<nb, blk, 0, stream>>>(x, Wl1, t4A, t1A);
    bucket_gather<10, 5, 5, true, true><<<gb, blk, 0, stream>>>(
        bcnt, bstore, t4A, t1A, x, Wr1, b1, Wlm, inv, hA, t4B, t1B);

    // ---- middle layers 0..6 (5 -> 5) ----
    const float4* t4c = t4B; const float* t1c = t1B;
    float4* t4n = t4A; float* t1n = t1A;
    const float* hcur = hA; float* hnext = hB;
    for (int mi = 0; mi < 7; ++mi) {
        bucket_gather<5, 5, 5, true, false><<<gb, blk, 0, stream>>>(
            bcnt, bstore, t4c, t1c, hcur, Wrm + mi * 25, bm + mi * 5,
            Wlm + (mi + 1) * 25, inv, hnext, t4n, t1n);
        const float4* a4 = t4c; t4c = t4n; t4n = (float4*)a4;
        const float*  a1 = t1c; t1c = t1n; t1n = (float*)a1;
        const float*  ah = hcur; hcur = hnext; hnext = (float*)ah;
    }
    // ---- middle layer 7: next pre-transform is final (5 -> 1) -> t1 plane only ----
    bucket_gather<5, 5, 1, true, false><<<gb, blk, 0, stream>>>(
        bcnt, bstore, t4c, t1c, hcur, Wrm + 7 * 25, bm + 7 * 5,
        Wl10, inv, hnext, nullptr, t1n);
    // ---- final layer (5 -> 1), no relu; t1 plane is 2 MB -> L2-resident ----
    bucket_gather<5, 1, 0, false, false><<<gb, blk, 0, stream>>>(
        bcnt, bstore, nullptr, t1n, hnext, Wr10, b10, nullptr, inv, out,
        nullptr, nullptr);
}